// Round 2
// 1878.834 us; speedup vs baseline: 1.0303x; 1.0303x over previous
//
#include <hip/hip_runtime.h>
#include <cstdint>
#include <cstddef>

// ---------------- problem constants ----------------
#define N_TOK 32768     // 16*2048 rows
#define DDIM  256       // feature dim
#define KCODE 4096      // codebook size

// output layout (floats) in d_out, reference tuple order:
// [0] vq_loss | [1..8388609) quantized_st | [8388609..142606337) soft_probs
// [142606337] perplexity | [142606338..142639106) encoding_indices
// [142639106] active_codes | [142639107] usage_pct
#define OUT_Q     1
#define OUT_PROBS 8388609
#define OUT_PERP  142606337
#define OUT_IDX   142606338
#define OUT_ACT   142639106
#define OUT_USE   142639107

// ---------------- workspace layout (bytes) ----------------
#define OFF_ACC      0          // 16 floats (acc[0] = sum of dmin)
#define OFF_COUNTS   64         // 4096 floats
#define OFF_ROWIDX   278592     // 32768 int
#define OFF_CBN      409664     // 4096*256 float (normalized codebook, fp32)
#define OFF_CBHI     4603968    // 4096*256 bf16 (hi)
#define OFF_CBLO     6701120    // 4096*256 bf16 (lo)
#define OFF_FHI      8798272    // 32768*256 bf16 (hi)
#define OFF_FLO      25575488   // 32768*256 bf16 (lo)

typedef __attribute__((ext_vector_type(8))) short bf16x8;
typedef __attribute__((ext_vector_type(16))) float f32x16;

__device__ __forceinline__ short f2bf(float f) {  // round-to-nearest-even fp32->bf16
  uint32_t u = __float_as_uint(f);
  u += 0x7fffu + ((u >> 16) & 1u);
  return (short)(u >> 16);
}
__device__ __forceinline__ float bf2f(short h) {
  return __uint_as_float(((uint32_t)(uint16_t)h) << 16);
}

// ---------------- row L2-normalize + hi/lo bf16 split ----------------
// block = 256 threads = 4 waves, one wave per row (64 lanes x 4 elems)
__global__ void vq_norm(const float* __restrict__ x, short* __restrict__ hi,
                        short* __restrict__ lo, float* __restrict__ outf) {
  int row  = blockIdx.x * 4 + (threadIdx.x >> 6);
  int lane = threadIdx.x & 63;
  const float4 v = *(const float4*)(x + (size_t)row * DDIM + lane * 4);
  float ss = v.x * v.x + v.y * v.y + v.z * v.z + v.w * v.w;
#pragma unroll
  for (int off = 1; off < 64; off <<= 1) ss += __shfl_xor(ss, off, 64);
  float sc = 1.0f / fmaxf(sqrtf(ss), 1e-12f);
  float n0 = v.x * sc, n1 = v.y * sc, n2 = v.z * sc, n3 = v.w * sc;
  if (outf) *(float4*)(outf + (size_t)row * DDIM + lane * 4) = make_float4(n0, n1, n2, n3);
  short h0 = f2bf(n0), h1 = f2bf(n1), h2 = f2bf(n2), h3 = f2bf(n3);
  short l0 = f2bf(n0 - bf2f(h0)), l1 = f2bf(n1 - bf2f(h1));
  short l2 = f2bf(n2 - bf2f(h2)), l3 = f2bf(n3 - bf2f(h3));
  *(short4*)(hi + (size_t)row * DDIM + lane * 4) = make_short4(h0, h1, h2, h3);
  *(short4*)(lo + (size_t)row * DDIM + lane * 4) = make_short4(l0, l1, l2, l3);
}

// ---------------- fused distance GEMM + softmax, two sweeps ----------------
// 3-pass split-bf16 MFMA (hi*hi + lo*hi + hi*lo): ~fp32-exact distances.
// block = 256 thr = 4 waves = 2 row-groups x 2 col-halves; block owns 64 rows.
// grid = 512 blocks -> 2 blocks/CU (LDS ~67 KB) for cross-block latency hiding.
// Sweep 1: online min/argmin/sumexp only (no global writes).
// Cross-wave merge (col halves) via small LDS buffer.
// Sweep 2: recompute distances (A-frags still in regs), write probs directly.
__global__ __launch_bounds__(256, 2) void vq_main(
    const short* __restrict__ fhi, const short* __restrict__ flo,
    const short* __restrict__ chi, const short* __restrict__ clo,
    float* __restrict__ probs, int* __restrict__ row_idx, float* __restrict__ accv) {
  __shared__ __align__(16) short Bh[64 * 256];
  __shared__ __align__(16) short Bl[64 * 256];
  __shared__ float Pm[4][32];
  __shared__ float Ps[4][32];
  __shared__ int   Pc[4][32];
  const int tid  = threadIdx.x;
  const int lane = tid & 63;
  const int w    = tid >> 6;
  const int l31  = lane & 31;
  const int q    = lane >> 5;
  const int ch   = w & 1;                        // column half of the 64-col tile
  const int rbase = blockIdx.x * 64 + (w >> 1) * 32;
  const int arow  = rbase + l31;   // A layout: row = lane%32, k = 8*(lane/32)+j

  bf16x8 ahi[16], alo[16];
#pragma unroll
  for (int kk = 0; kk < 16; ++kk) {
    size_t off = (size_t)arow * DDIM + kk * 16 + q * 8;
    ahi[kk] = *(const bf16x8*)(fhi + off);
    alo[kk] = *(const bf16x8*)(flo + off);
  }

  float m[16], s[16];
  int   c[16];
#pragma unroll
  for (int r = 0; r < 16; ++r) { m[r] = 1e30f; s[r] = 0.0f; c[r] = 0; }

  // ---------------- sweep 1: min / argmin / sumexp ----------------
  for (int jt = 0; jt < 64; ++jt) {
    const int c0 = jt * 64;
    __syncthreads();
#pragma unroll
    for (int it = 0; it < 8; ++it) {           // stage 64 KB (hi+lo) into LDS
      int ci = tid + 256 * it;                 // 2048 16B-chunks per matrix
      int lc = ci >> 5;                        // local col 0..63
      int kc = ci & 31;                        // k-chunk 0..31
      int sw = kc ^ (lc & 31);                 // full-width XOR: conflict-free reads
      size_t goff = (size_t)(c0 + lc) * DDIM + kc * 8;
      int4 vh = *(const int4*)(chi + goff);
      int4 vl = *(const int4*)(clo + goff);
      *(int4*)(&Bh[lc * 256 + sw * 8]) = vh;
      *(int4*)(&Bl[lc * 256 + sw * 8]) = vl;
    }
    __syncthreads();

    f32x16 acc = (f32x16)0.0f;
#pragma unroll
    for (int kk = 0; kk < 16; ++kk) {
      int kc = kk * 2 + q;
      int sw = (kc ^ l31) * 8;                 // (col&31) == l31 for both halves
      const bf16x8 bh = *(const bf16x8*)(&Bh[(32 * ch + l31) * 256 + sw]);
      const bf16x8 bl = *(const bf16x8*)(&Bl[(32 * ch + l31) * 256 + sw]);
      acc = __builtin_amdgcn_mfma_f32_32x32x16_bf16(ahi[kk], bh, acc, 0, 0, 0);
      acc = __builtin_amdgcn_mfma_f32_32x32x16_bf16(alo[kk], bh, acc, 0, 0, 0);
      acc = __builtin_amdgcn_mfma_f32_32x32x16_bf16(ahi[kk], bl, acc, 0, 0, 0);
    }
    const int col = c0 + 32 * ch + l31;        // one column per lane per tile
#pragma unroll
    for (int r = 0; r < 16; ++r) {
      float d  = 2.0f - 2.0f * acc[r];
      float mo = m[r];
      if (d < mo) {                            // new min: rescale old sum
        s[r] = s[r] * __expf(d - mo) + 1.0f;   // first iter: 0*exp(-1e30)=0, ok
        m[r] = d; c[r] = col;                  // ascending cols: strict < keeps lowest
      } else {
        s[r] += __expf(mo - d);
      }
    }
  }

  // merge per-lane partial state across the 32 lanes sharing q (cols of each row)
#pragma unroll
  for (int off = 1; off < 32; off <<= 1) {
#pragma unroll
    for (int r = 0; r < 16; ++r) {
      float mo = __shfl_xor(m[r], off, 64);
      float so = __shfl_xor(s[r], off, 64);
      int   co = __shfl_xor(c[r], off, 64);
      float nm = fminf(m[r], mo);
      s[r] = s[r] * __expf(nm - m[r]) + so * __expf(nm - mo);
      if (mo < m[r] || (mo == m[r] && co < c[r])) c[r] = co;
      m[r] = nm;
    }
  }

  // merge the two column-half waves of each row-group via LDS
  __syncthreads();
  if (l31 == 0) {
#pragma unroll
    for (int r = 0; r < 16; ++r) {
      int rl = 4 * q + (r & 3) + 8 * (r >> 2);  // verified 32x32 C/D row map
      Pm[w][rl] = m[r]; Ps[w][rl] = s[r]; Pc[w][rl] = c[r];
    }
  }
  __syncthreads();
#pragma unroll
  for (int r = 0; r < 16; ++r) {
    int rl = 4 * q + (r & 3) + 8 * (r >> 2);
    float mo = Pm[w ^ 1][rl];
    float so = Ps[w ^ 1][rl];
    int   co = Pc[w ^ 1][rl];
    float nm = fminf(m[r], mo);
    s[r] = s[r] * __expf(nm - m[r]) + so * __expf(nm - mo);
    if (mo < m[r] || (mo == m[r] && co < c[r])) c[r] = co;
    m[r] = nm;
  }

  if (ch == 0) {                               // one wave per row-group writes
    float vsum = 0.0f;
#pragma unroll
    for (int r = 0; r < 16; ++r) vsum += m[r];
    vsum += __shfl_xor(vsum, 32, 64);          // combine q=0/q=1 halves
    if (lane == 0) atomicAdd(accv, vsum);      // sum of dmin -> vq_loss
    if (l31 == 0) {
#pragma unroll
      for (int r = 0; r < 16; ++r) {
        int rl = 4 * q + (r & 3) + 8 * (r >> 2);
        row_idx[rbase + rl] = c[r];
      }
    }
  }

  // per-row constants for sweep 2: probs = exp(m - 2 + 2*acc) / s
  float m2[16], is[16];
#pragma unroll
  for (int r = 0; r < 16; ++r) { m2[r] = m[r] - 2.0f; is[r] = 1.0f / s[r]; }

  // ---------------- sweep 2: recompute distances, write probs ----------------
  for (int jt = 0; jt < 64; ++jt) {
    const int c0 = jt * 64;
    __syncthreads();
#pragma unroll
    for (int it = 0; it < 8; ++it) {
      int ci = tid + 256 * it;
      int lc = ci >> 5;
      int kc = ci & 31;
      int sw = kc ^ (lc & 31);
      size_t goff = (size_t)(c0 + lc) * DDIM + kc * 8;
      int4 vh = *(const int4*)(chi + goff);
      int4 vl = *(const int4*)(clo + goff);
      *(int4*)(&Bh[lc * 256 + sw * 8]) = vh;
      *(int4*)(&Bl[lc * 256 + sw * 8]) = vl;
    }
    __syncthreads();

    f32x16 acc = (f32x16)0.0f;
#pragma unroll
    for (int kk = 0; kk < 16; ++kk) {
      int kc = kk * 2 + q;
      int sw = (kc ^ l31) * 8;
      const bf16x8 bh = *(const bf16x8*)(&Bh[(32 * ch + l31) * 256 + sw]);
      const bf16x8 bl = *(const bf16x8*)(&Bl[(32 * ch + l31) * 256 + sw]);
      acc = __builtin_amdgcn_mfma_f32_32x32x16_bf16(ahi[kk], bh, acc, 0, 0, 0);
      acc = __builtin_amdgcn_mfma_f32_32x32x16_bf16(alo[kk], bh, acc, 0, 0, 0);
      acc = __builtin_amdgcn_mfma_f32_32x32x16_bf16(ahi[kk], bl, acc, 0, 0, 0);
    }
#pragma unroll
    for (int r = 0; r < 16; ++r) {
      int row = rbase + 4 * q + (r & 3) + 8 * (r >> 2);
      float p = __expf(fmaf(2.0f, acc[r], m2[r])) * is[r];
      probs[(size_t)row * KCODE + c0 + 32 * ch + l31] = p;
    }
  }
}

// ---------------- gather quantized rows + counts + indices ----------------
__global__ void vq_gather(const float* __restrict__ cbn, const int* __restrict__ row_idx,
                          float* __restrict__ outq, float* __restrict__ outidx,
                          float* __restrict__ counts) {
  int row  = blockIdx.x * 4 + (threadIdx.x >> 6);
  int lane = threadIdx.x & 63;
  int idx  = row_idx[row];
#pragma unroll
  for (int j = 0; j < 4; ++j)
    outq[(size_t)row * DDIM + j * 64 + lane] = cbn[(size_t)idx * DDIM + j * 64 + lane];
  if (lane == 0) {
    outidx[row] = (float)idx;
    atomicAdd(&counts[idx], 1.0f);
  }
}

// ---------------- scalars: vq_loss, perplexity, active, usage ----------------
__global__ void vq_final(const float* __restrict__ counts, const float* __restrict__ accv,
                         float* __restrict__ out) {
  int tid = threadIdx.x;
  float e = 0.0f, a = 0.0f;
  for (int k = tid; k < KCODE; k += 256) {
    float cnt = counts[k];
    float p = cnt * (1.0f / 32768.0f);
    e += p * logf(p + 1e-10f);
    a += (cnt > 0.0f) ? 1.0f : 0.0f;
  }
#pragma unroll
  for (int off = 1; off < 64; off <<= 1) {
    e += __shfl_xor(e, off, 64);
    a += __shfl_xor(a, off, 64);
  }
  __shared__ float re[4], ra[4];
  if ((tid & 63) == 0) { re[tid >> 6] = e; ra[tid >> 6] = a; }
  __syncthreads();
  if (tid == 0) {
    float et = re[0] + re[1] + re[2] + re[3];
    float at = ra[0] + ra[1] + ra[2] + ra[3];
    out[0]        = 0.25f * accv[0] * (1.0f / (32768.0f * 256.0f));
    out[OUT_PERP] = expf(-et);
    out[OUT_ACT]  = at;
    out[OUT_USE]  = at * (100.0f / 4096.0f);
  }
}

extern "C" void kernel_launch(void* const* d_in, const int* in_sizes, int n_in,
                              void* d_out, int out_size, void* d_ws, size_t ws_size,
                              hipStream_t stream) {
  const float* x  = (const float*)d_in[0];   // (16,2048,256) fp32
  const float* wt = (const float*)d_in[1];   // (4096,256) fp32
  float* out = (float*)d_out;
  char*  ws  = (char*)d_ws;

  float*  accv    = (float*)(ws + OFF_ACC);
  float*  counts  = (float*)(ws + OFF_COUNTS);
  int*    row_idx = (int*)(ws + OFF_ROWIDX);
  float*  cbn     = (float*)(ws + OFF_CBN);
  short*  chi     = (short*)(ws + OFF_CBHI);
  short*  clo     = (short*)(ws + OFF_CBLO);
  short*  fhi     = (short*)(ws + OFF_FHI);
  short*  flo     = (short*)(ws + OFF_FLO);

  float* out_q   = out + OUT_Q;
  float* probs   = out + OUT_PROBS;
  float* out_idx = out + OUT_IDX;

  hipMemsetAsync(ws, 0, OFF_COUNTS + KCODE * 4, stream);       // acc + counts
  vq_norm<<<N_TOK / 4, 256, 0, stream>>>(x, fhi, flo, nullptr);
  vq_norm<<<KCODE / 4, 256, 0, stream>>>(wt, chi, clo, cbn);
  vq_main<<<N_TOK / 64, 256, 0, stream>>>(fhi, flo, chi, clo, probs, row_idx, accv);
  vq_gather<<<N_TOK / 4, 256, 0, stream>>>(cbn, row_idx, out_q, out_idx, counts);
  vq_final<<<1, 256, 0, stream>>>(counts, accv, out);
}

// Round 3
// 1399.781 us; speedup vs baseline: 1.3829x; 1.3422x over previous
//
#include <hip/hip_runtime.h>
#include <cstdint>
#include <cstddef>

// ---------------- problem constants ----------------
#define N_TOK 32768     // 16*2048 rows
#define DDIM  256       // feature dim
#define KCODE 4096      // codebook size

// output layout (floats) in d_out, reference tuple order
#define OUT_Q     1
#define OUT_PROBS 8388609
#define OUT_PERP  142606337
#define OUT_IDX   142606338
#define OUT_ACT   142639106
#define OUT_USE   142639107

// ---------------- workspace layout (bytes) ----------------
#define OFF_ACC      0          // 16 floats (acc[0] = sum of dmin)
#define OFF_COUNTS   64         // 4096 floats
#define OFF_ROWIDX   278592     // 32768 int
#define OFF_CBN      409664     // 4096*256 float (normalized codebook, fp32)
#define OFF_CBHI     4603968    // 4096*256 bf16 (hi)
#define OFF_CBLO     6701120    // 4096*256 bf16 (lo)
#define OFF_FHI      8798272    // 32768*256 bf16 (hi)
#define OFF_FLO      25575488   // 32768*256 bf16 (lo)

typedef __attribute__((ext_vector_type(8))) short bf16x8;
typedef __attribute__((ext_vector_type(16))) float f32x16;

__device__ __forceinline__ short f2bf(float f) {  // round-to-nearest-even fp32->bf16
  uint32_t u = __float_as_uint(f);
  u += 0x7fffu + ((u >> 16) & 1u);
  return (short)(u >> 16);
}
__device__ __forceinline__ float bf2f(short h) {
  return __uint_as_float(((uint32_t)(uint16_t)h) << 16);
}

// direct global->LDS 16B copy (dest = wave-uniform base + lane*16, linear)
__device__ __forceinline__ void gload16(const void* g, void* l) {
  __builtin_amdgcn_global_load_lds(
      (const __attribute__((address_space(1))) unsigned int*)g,
      (__attribute__((address_space(3))) unsigned int*)l, 16, 0, 0);
}

// ---------------- row L2-normalize + hi/lo bf16 split ----------------
__global__ void vq_norm(const float* __restrict__ x, short* __restrict__ hi,
                        short* __restrict__ lo, float* __restrict__ outf) {
  int row  = blockIdx.x * 4 + (threadIdx.x >> 6);
  int lane = threadIdx.x & 63;
  const float4 v = *(const float4*)(x + (size_t)row * DDIM + lane * 4);
  float ss = v.x * v.x + v.y * v.y + v.z * v.z + v.w * v.w;
#pragma unroll
  for (int off = 1; off < 64; off <<= 1) ss += __shfl_xor(ss, off, 64);
  float sc = 1.0f / fmaxf(sqrtf(ss), 1e-12f);
  float n0 = v.x * sc, n1 = v.y * sc, n2 = v.z * sc, n3 = v.w * sc;
  if (outf) *(float4*)(outf + (size_t)row * DDIM + lane * 4) = make_float4(n0, n1, n2, n3);
  short h0 = f2bf(n0), h1 = f2bf(n1), h2 = f2bf(n2), h3 = f2bf(n3);
  short l0 = f2bf(n0 - bf2f(h0)), l1 = f2bf(n1 - bf2f(h1));
  short l2 = f2bf(n2 - bf2f(h2)), l3 = f2bf(n3 - bf2f(h3));
  *(short4*)(hi + (size_t)row * DDIM + lane * 4) = make_short4(h0, h1, h2, h3);
  *(short4*)(lo + (size_t)row * DDIM + lane * 4) = make_short4(l0, l1, l2, l3);
}

// ---------------- fused distance GEMM + softmax, two sweeps ----------------
// block = 512 thr = 8 waves = 4 row-groups x 2 col-halves; block owns 128 rows.
// grid = 256 -> 1 block/CU. LDS = 2 x (64 cols x 256 k x bf16 hi+lo) = 128 KB,
// double-buffered; stage tile t+1 via global_load_lds while computing tile t.
// A-fragments pinned in VGPRs via asm (prevents rematerialized global reloads).
__global__ __launch_bounds__(512, 2) void vq_main(
    const short* __restrict__ fhi, const short* __restrict__ flo,
    const short* __restrict__ chi, const short* __restrict__ clo,
    float* __restrict__ probs, int* __restrict__ row_idx, float* __restrict__ accv) {
  __shared__ __align__(16) short Bs[2][2][64 * 256];   // [dbuf][hi/lo][col*256 + k]
  // merge scratch aliased onto buffer 0 (only used between the two sweeps)
  float* Pm = (float*)&Bs[0][0][0];          // 8*32 floats
  float* Ps = Pm + 256;                      // 8*32 floats
  int*   Pc = (int*)(Ps + 256);              // 8*32 ints

  const int tid  = threadIdx.x;
  const int lane = tid & 63;
  const int w    = tid >> 6;
  const int l31  = lane & 31;
  const int q    = lane >> 5;
  const int ch   = w & 1;                       // column half of the 64-col tile
  const int rbase = blockIdx.x * 128 + (w >> 1) * 32;
  const int arow  = rbase + l31;  // A layout: row = lane%32, k = 8*(lane/32)+j

  bf16x8 ahi[16], alo[16];
#pragma unroll
  for (int kk = 0; kk < 16; ++kk) {
    size_t off = (size_t)arow * DDIM + kk * 16 + q * 8;
    ahi[kk] = *(const bf16x8*)(fhi + off);
    alo[kk] = *(const bf16x8*)(flo + off);
  }
#pragma unroll
  for (int kk = 0; kk < 16; ++kk) {          // pin: forbid remat/reload of A
    asm volatile("" : "+v"(ahi[kk]), "+v"(alo[kk]));
  }

  // stage one 64-col tile (hi+lo, 64 KB) into LDS buffer `buf`.
  // dest is linear (global_load_lds requirement); source address carries the
  // inverse XOR swizzle so reads below stay bank-conflict-free.
  auto STAGE = [&](int jt, int buf) {
    const int c0 = jt * 64;
#pragma unroll
    for (int i = 0; i < 4; ++i) {
      int chunk = tid + 512 * i;               // 2048 16B-chunks per matrix
      int lc  = chunk >> 5;                    // local col 0..63
      int swc = chunk & 31;                    // dest k-chunk slot (linear)
      int kc  = swc ^ (lc & 31);               // source k-chunk (pre-swizzled)
      size_t goff = (size_t)(c0 + lc) * DDIM + kc * 8;
      gload16(chi + goff, &Bs[buf][0][chunk * 8]);
      gload16(clo + goff, &Bs[buf][1][chunk * 8]);
    }
  };

  // 3-pass split-bf16 distance GEMM for one tile: acc = dot(row, col)
  auto GEMM = [&](int buf) -> f32x16 {
    f32x16 acc = (f32x16)0.0f;
    const short* bb = &Bs[buf][0][(32 * ch + l31) * 256];
#pragma unroll
    for (int kk = 0; kk < 16; ++kk) {
      int sw = ((kk * 2 + q) ^ l31) * 8;
      const bf16x8 bh = *(const bf16x8*)(bb + sw);
      const bf16x8 bl = *(const bf16x8*)(bb + 16384 + sw);
      acc = __builtin_amdgcn_mfma_f32_32x32x16_bf16(ahi[kk], bh, acc, 0, 0, 0);
      acc = __builtin_amdgcn_mfma_f32_32x32x16_bf16(alo[kk], bh, acc, 0, 0, 0);
      acc = __builtin_amdgcn_mfma_f32_32x32x16_bf16(ahi[kk], bl, acc, 0, 0, 0);
    }
    return acc;
  };

  float m[16], s[16];
  int   c[16];
#pragma unroll
  for (int r = 0; r < 16; ++r) { m[r] = 1e30f; s[r] = 0.0f; c[r] = 0; }

  // ---------------- sweep 1: min / argmin / sumexp ----------------
  STAGE(0, 0);
  __syncthreads();
  for (int jt = 0; jt < 64; ++jt) {
    const int buf = jt & 1;
    if (jt < 63) STAGE(jt + 1, buf ^ 1);       // prefetch under compute
    f32x16 acc = GEMM(buf);
    const int col = jt * 64 + 32 * ch + l31;   // one column per lane per tile
#pragma unroll
    for (int r = 0; r < 16; ++r) {
      float d  = 2.0f - 2.0f * acc[r];
      float mo = m[r];
      if (d < mo) {                            // new min: rescale old sum
        s[r] = s[r] * __expf(d - mo) + 1.0f;   // first iter: 0*exp(-1e30)=0, ok
        m[r] = d; c[r] = col;                  // ascending cols: < keeps lowest
      } else {
        s[r] += __expf(mo - d);
      }
    }
    __syncthreads();                           // prefetch landed + buf consumed
  }

  // merge per-lane partials across the 32 lanes sharing q (cols of each row)
#pragma unroll
  for (int off = 1; off < 32; off <<= 1) {
#pragma unroll
    for (int r = 0; r < 16; ++r) {
      float mo = __shfl_xor(m[r], off, 64);
      float so = __shfl_xor(s[r], off, 64);
      int   co = __shfl_xor(c[r], off, 64);
      float nm = fminf(m[r], mo);
      s[r] = s[r] * __expf(nm - m[r]) + so * __expf(nm - mo);
      if (mo < m[r] || (mo == m[r] && co < c[r])) c[r] = co;
      m[r] = nm;
    }
  }

  // merge the two column-half waves of each row-group via aliased LDS scratch
  if (l31 == 0) {
#pragma unroll
    for (int r = 0; r < 16; ++r) {
      int rl = 4 * q + (r & 3) + 8 * (r >> 2); // verified 32x32 C/D row map
      Pm[w * 32 + rl] = m[r]; Ps[w * 32 + rl] = s[r]; Pc[w * 32 + rl] = c[r];
    }
  }
  __syncthreads();
#pragma unroll
  for (int r = 0; r < 16; ++r) {
    int rl = 4 * q + (r & 3) + 8 * (r >> 2);
    float mo = Pm[(w ^ 1) * 32 + rl];
    float so = Ps[(w ^ 1) * 32 + rl];
    int   co = Pc[(w ^ 1) * 32 + rl];
    float nm = fminf(m[r], mo);
    s[r] = s[r] * __expf(nm - m[r]) + so * __expf(nm - mo);
    if (mo < m[r] || (mo == m[r] && co < c[r])) c[r] = co;
    m[r] = nm;
  }

  if (ch == 0) {                               // one wave per row-group writes
    float vsum = 0.0f;
#pragma unroll
    for (int r = 0; r < 16; ++r) vsum += m[r];
    vsum += __shfl_xor(vsum, 32, 64);          // combine q=0/q=1 halves
    if (lane == 0) atomicAdd(accv, vsum);      // sum of dmin -> vq_loss
    if (l31 == 0) {
#pragma unroll
      for (int r = 0; r < 16; ++r) {
        int rl = 4 * q + (r & 3) + 8 * (r >> 2);
        row_idx[rbase + rl] = c[r];
      }
    }
  }

  // per-row constants for sweep 2: probs = exp(m - 2 + 2*acc) / s
  float m2[16], is[16];
#pragma unroll
  for (int r = 0; r < 16; ++r) { m2[r] = m[r] - 2.0f; is[r] = 1.0f / s[r]; }

  // ---------------- sweep 2: recompute distances, write probs ----------------
  __syncthreads();                             // merge reads done before overwrite
  STAGE(0, 0);
  __syncthreads();
  for (int jt = 0; jt < 64; ++jt) {
    const int buf = jt & 1;
    if (jt < 63) STAGE(jt + 1, buf ^ 1);
    f32x16 acc = GEMM(buf);
#pragma unroll
    for (int r = 0; r < 16; ++r) {
      int row = rbase + 4 * q + (r & 3) + 8 * (r >> 2);
      float p = __expf(fmaf(2.0f, acc[r], m2[r])) * is[r];
      // nt store: probs region is +4B-misaligned; bypass L2 write-allocate
      __builtin_nontemporal_store(
          p, &probs[(size_t)row * KCODE + jt * 64 + 32 * ch + l31]);
    }
    __syncthreads();
  }
}

// ---------------- gather quantized rows + counts + indices ----------------
__global__ void vq_gather(const float* __restrict__ cbn, const int* __restrict__ row_idx,
                          float* __restrict__ outq, float* __restrict__ outidx,
                          float* __restrict__ counts) {
  int row  = blockIdx.x * 4 + (threadIdx.x >> 6);
  int lane = threadIdx.x & 63;
  int idx  = row_idx[row];
#pragma unroll
  for (int j = 0; j < 4; ++j)
    outq[(size_t)row * DDIM + j * 64 + lane] = cbn[(size_t)idx * DDIM + j * 64 + lane];
  if (lane == 0) {
    outidx[row] = (float)idx;
    atomicAdd(&counts[idx], 1.0f);
  }
}

// ---------------- scalars: vq_loss, perplexity, active, usage ----------------
__global__ void vq_final(const float* __restrict__ counts, const float* __restrict__ accv,
                         float* __restrict__ out) {
  int tid = threadIdx.x;
  float e = 0.0f, a = 0.0f;
  for (int k = tid; k < KCODE; k += 256) {
    float cnt = counts[k];
    float p = cnt * (1.0f / 32768.0f);
    e += p * logf(p + 1e-10f);
    a += (cnt > 0.0f) ? 1.0f : 0.0f;
  }
#pragma unroll
  for (int off = 1; off < 64; off <<= 1) {
    e += __shfl_xor(e, off, 64);
    a += __shfl_xor(a, off, 64);
  }
  __shared__ float re[4], ra[4];
  if ((tid & 63) == 0) { re[tid >> 6] = e; ra[tid >> 6] = a; }
  __syncthreads();
  if (tid == 0) {
    float et = re[0] + re[1] + re[2] + re[3];
    float at = ra[0] + ra[1] + ra[2] + ra[3];
    out[0]        = 0.25f * accv[0] * (1.0f / (32768.0f * 256.0f));
    out[OUT_PERP] = expf(-et);
    out[OUT_ACT]  = at;
    out[OUT_USE]  = at * (100.0f / 4096.0f);
  }
}

extern "C" void kernel_launch(void* const* d_in, const int* in_sizes, int n_in,
                              void* d_out, int out_size, void* d_ws, size_t ws_size,
                              hipStream_t stream) {
  const float* x  = (const float*)d_in[0];   // (16,2048,256) fp32
  const float* wt = (const float*)d_in[1];   // (4096,256) fp32
  float* out = (float*)d_out;
  char*  ws  = (char*)d_ws;

  float*  accv    = (float*)(ws + OFF_ACC);
  float*  counts  = (float*)(ws + OFF_COUNTS);
  int*    row_idx = (int*)(ws + OFF_ROWIDX);
  float*  cbn     = (float*)(ws + OFF_CBN);
  short*  chi     = (short*)(ws + OFF_CBHI);
  short*  clo     = (short*)(ws + OFF_CBLO);
  short*  fhi     = (short*)(ws + OFF_FHI);
  short*  flo     = (short*)(ws + OFF_FLO);

  float* out_q   = out + OUT_Q;
  float* probs   = out + OUT_PROBS;
  float* out_idx = out + OUT_IDX;

  hipMemsetAsync(ws, 0, OFF_COUNTS + KCODE * 4, stream);       // acc + counts
  vq_norm<<<N_TOK / 4, 256, 0, stream>>>(x, fhi, flo, nullptr);
  vq_norm<<<KCODE / 4, 256, 0, stream>>>(wt, chi, clo, cbn);
  vq_main<<<N_TOK / 128, 512, 0, stream>>>(fhi, flo, chi, clo, probs, row_idx, accv);
  vq_gather<<<N_TOK / 4, 256, 0, stream>>>(cbn, row_idx, out_q, out_idx, counts);
  vq_final<<<1, 256, 0, stream>>>(counts, accv, out);
}